// Round 1
// baseline (6233.412 us; speedup 1.0000x reference)
//
#include <hip/hip_runtime.h>
#include <math.h>

#define Bn 4096
#define Dn 1024
#define Cn 11003
#define NCT 172   // ceil(Cn/64)
#define NQ 9

// ---------- helpers ----------
__device__ __forceinline__ float blk_sum256(float v, volatile float* sb) {
#pragma unroll
  for (int o = 32; o > 0; o >>= 1) v += __shfl_down(v, o, 64);
  __syncthreads();
  if ((threadIdx.x & 63) == 0) sb[threadIdx.x >> 6] = v;
  __syncthreads();
  return sb[0] + sb[1] + sb[2] + sb[3];
}

__global__ void zero_acc_k(float* acc) {
  if (threadIdx.x < 8) acc[threadIdx.x] = 0.f;
}

// ---------- row L2 normalize + exact post-norm sumsq ----------
__global__ __launch_bounds__(256) void rownorm_k(const float* __restrict__ x,
                                                 float* __restrict__ y,
                                                 float* __restrict__ sq) {
  __shared__ float sb[4];
  int r = blockIdx.x;
  const float* xr = x + (size_t)r * Dn;
  float* yr = y + (size_t)r * Dn;
  float s = 0.f;
  for (int k = threadIdx.x; k < Dn; k += 256) { float v = xr[k]; s += v * v; }
  s = blk_sum256(s, sb);
  float nrm = sqrtf(s);
  float s2 = 0.f;
  for (int k = threadIdx.x; k < Dn; k += 256) {
    float v = xr[k] / nrm;
    yr[k] = v;
    s2 += v * v;
  }
  s2 = blk_sum256(s2, sb);
  if (threadIdx.x == 0) sq[r] = s2;
}

// ---------- column L2 normalize of W [Dn x Cn] ----------
__global__ __launch_bounds__(256) void colnorm_k(const float* __restrict__ W,
                                                 float* __restrict__ Wn) {
  int c = blockIdx.x * 256 + threadIdx.x;
  if (c >= Cn) return;
  float s = 0.f;
  for (int d = 0; d < Dn; ++d) { float v = W[(size_t)d * Cn + c]; s += v * v; }
  float nrm = sqrtf(s);
  for (int d = 0; d < Dn; ++d) Wn[(size_t)d * Cn + c] = W[(size_t)d * Cn + c] / nrm;
}

// ---------- fused triple logits GEMM with 9-quantity row reductions ----------
// V = 28*vn@Wn, Te = 28*tn@Wn, F = 28*tn@Wtn over 64x64 tiles.
// part[q][ct][row] partials; shift 28 is a valid upper bound on all logits.
__global__ __launch_bounds__(256) void logits_k(const float* __restrict__ vn,
                                                const float* __restrict__ tn,
                                                const float* __restrict__ Wn,
                                                const float* __restrict__ Wtn,
                                                float* __restrict__ part) {
  __shared__ __align__(16) float As[2][16][68];
  __shared__ __align__(16) float Bs[2][16][68];
  __shared__ float red[64][17];

  const int ct = blockIdx.x, rt = blockIdx.y;
  const int c0 = ct * 64, r0 = rt * 64;
  const int tid = threadIdx.x;
  const int tx = tid & 15, ty = tid >> 4;

  float aV[4][4] = {{0.f}}, aT[4][4] = {{0.f}}, aF[4][4] = {{0.f}};

  const int lr = tid >> 2, lk = (tid & 3) * 4;  // A-tile loader mapping
  const int bc = tid & 63, bk = tid >> 6;       // B-tile loader mapping

  for (int k0 = 0; k0 < Dn; k0 += 16) {
    float4 av = *(const float4*)(vn + (size_t)(r0 + lr) * Dn + k0 + lk);
    float4 at = *(const float4*)(tn + (size_t)(r0 + lr) * Dn + k0 + lk);
    As[0][lk + 0][lr] = av.x; As[0][lk + 1][lr] = av.y;
    As[0][lk + 2][lr] = av.z; As[0][lk + 3][lr] = av.w;
    As[1][lk + 0][lr] = at.x; As[1][lk + 1][lr] = at.y;
    As[1][lk + 2][lr] = at.z; As[1][lk + 3][lr] = at.w;
#pragma unroll
    for (int p = 0; p < 4; ++p) {
      int k = p * 4 + bk;
      int c = c0 + bc;
      float w0 = 0.f, w1 = 0.f;
      if (c < Cn) {
        w0 = Wn[(size_t)(k0 + k) * Cn + c];
        w1 = Wtn[(size_t)(k0 + k) * Cn + c];
      }
      Bs[0][k][bc] = w0;
      Bs[1][k][bc] = w1;
    }
    __syncthreads();
#pragma unroll
    for (int k = 0; k < 16; ++k) {
      float avr[4], atr[4], bw[4], bt[4];
#pragma unroll
      for (int j = 0; j < 4; ++j) {
        avr[j] = As[0][k][ty * 4 + j];
        atr[j] = As[1][k][ty * 4 + j];
        bw[j] = Bs[0][k][tx * 4 + j];
        bt[j] = Bs[1][k][tx * 4 + j];
      }
#pragma unroll
      for (int i = 0; i < 4; ++i)
#pragma unroll
        for (int j = 0; j < 4; ++j) {
          aV[i][j] = fmaf(avr[i], bw[j], aV[i][j]);
          aT[i][j] = fmaf(atr[i], bw[j], aT[i][j]);
          aF[i][j] = fmaf(atr[i], bt[j], aF[i][j]);
        }
    }
    __syncthreads();
  }

  // epilogue: 9 per-row quantities, reduced across the 16 col-threads
  for (int q = 0; q < NQ; ++q) {
    float pr[4] = {0.f, 0.f, 0.f, 0.f};
#pragma unroll
    for (int j = 0; j < 4; ++j) {
      int c = c0 + tx * 4 + j;
      if (c >= Cn) continue;
#pragma unroll
      for (int i = 0; i < 4; ++i) {
        float V = 28.f * aV[i][j], Te = 28.f * aT[i][j], F = 28.f * aF[i][j];
        float val;
        switch (q) {
          case 0: val = __expf(V - 28.f); break;
          case 1: val = V; break;
          case 2: val = __expf(Te - 28.f); break;
          case 3: val = Te; break;
          case 4: val = __expf(F - 28.f); break;
          case 5: val = F; break;
          case 6: val = __expf((V - 28.f) * 0.25f); break;
          case 7: val = __expf((Te - 28.f) * 0.25f); break;
          default: val = __expf((V - 28.f) * 0.25f) * (V - Te); break;
        }
        pr[i] += val;
      }
    }
    __syncthreads();
#pragma unroll
    for (int i = 0; i < 4; ++i) red[ty * 4 + i][tx] = pr[i];
    __syncthreads();
    if (tid < 64) {
      float s = 0.f;
#pragma unroll
      for (int t = 0; t < 16; ++t) s += red[tid][t];
      part[(size_t)q * ((size_t)NCT * Bn) + (size_t)ct * Bn + (r0 + tid)] = s;
    }
  }
}

// ---------- gram GEMM: G = A @ Bm^T (both [Bn x Dn] row-major) ----------
__global__ __launch_bounds__(256) void gram_k(const float* __restrict__ A,
                                              const float* __restrict__ Bm,
                                              float* __restrict__ G) {
  __shared__ __align__(16) float As[16][68];
  __shared__ __align__(16) float Bs[16][68];
  const int jt = blockIdx.x, it = blockIdx.y;
  const int j0 = jt * 64, i0 = it * 64;
  const int tid = threadIdx.x, tx = tid & 15, ty = tid >> 4;
  const int lr = tid >> 2, lk = (tid & 3) * 4;
  float acc[4][4] = {{0.f}};
  for (int k0 = 0; k0 < Dn; k0 += 16) {
    float4 a4 = *(const float4*)(A + (size_t)(i0 + lr) * Dn + k0 + lk);
    float4 b4 = *(const float4*)(Bm + (size_t)(j0 + lr) * Dn + k0 + lk);
    As[lk + 0][lr] = a4.x; As[lk + 1][lr] = a4.y;
    As[lk + 2][lr] = a4.z; As[lk + 3][lr] = a4.w;
    Bs[lk + 0][lr] = b4.x; Bs[lk + 1][lr] = b4.y;
    Bs[lk + 2][lr] = b4.z; Bs[lk + 3][lr] = b4.w;
    __syncthreads();
#pragma unroll
    for (int k = 0; k < 16; ++k) {
      float a[4], b[4];
#pragma unroll
      for (int j = 0; j < 4; ++j) {
        a[j] = As[k][ty * 4 + j];
        b[j] = Bs[k][tx * 4 + j];
      }
#pragma unroll
      for (int i = 0; i < 4; ++i)
#pragma unroll
        for (int j = 0; j < 4; ++j) acc[i][j] = fmaf(a[i], b[j], acc[i][j]);
    }
    __syncthreads();
  }
#pragma unroll
  for (int i = 0; i < 4; ++i) {
    float4 o = make_float4(acc[i][0], acc[i][1], acc[i][2], acc[i][3]);
    *(float4*)(G + (size_t)(i0 + ty * 4 + i) * Bn + j0 + tx * 4) = o;
  }
}

// ---------- global-align fused GEMM: sim = vn @ tn^T, loss reduced to accbuf[1] ----------
__global__ __launch_bounds__(256) void align_k(const float* __restrict__ vn,
                                               const float* __restrict__ tn,
                                               const int* __restrict__ labels,
                                               float* __restrict__ accbuf) {
  __shared__ __align__(16) float As[16][68];
  __shared__ __align__(16) float Bs[16][68];
  __shared__ float sb[4];
  const int jt = blockIdx.x, it = blockIdx.y;
  const int j0 = jt * 64, i0 = it * 64;
  const int tid = threadIdx.x, tx = tid & 15, ty = tid >> 4;
  const int lr = tid >> 2, lk = (tid & 3) * 4;
  float acc[4][4] = {{0.f}};
  for (int k0 = 0; k0 < Dn; k0 += 16) {
    float4 a4 = *(const float4*)(vn + (size_t)(i0 + lr) * Dn + k0 + lk);
    float4 b4 = *(const float4*)(tn + (size_t)(j0 + lr) * Dn + k0 + lk);
    As[lk + 0][lr] = a4.x; As[lk + 1][lr] = a4.y;
    As[lk + 2][lr] = a4.z; As[lk + 3][lr] = a4.w;
    Bs[lk + 0][lr] = b4.x; Bs[lk + 1][lr] = b4.y;
    Bs[lk + 2][lr] = b4.z; Bs[lk + 3][lr] = b4.w;
    __syncthreads();
#pragma unroll
    for (int k = 0; k < 16; ++k) {
      float a[4], b[4];
#pragma unroll
      for (int j = 0; j < 4; ++j) {
        a[j] = As[k][ty * 4 + j];
        b[j] = Bs[k][tx * 4 + j];
      }
#pragma unroll
      for (int i = 0; i < 4; ++i)
#pragma unroll
        for (int j = 0; j < 4; ++j) acc[i][j] = fmaf(a[i], b[j], acc[i][j]);
    }
    __syncthreads();
  }
  int li[4], lj[4];
#pragma unroll
  for (int i = 0; i < 4; ++i) li[i] = labels[i0 + ty * 4 + i];
#pragma unroll
  for (int j = 0; j < 4; ++j) lj[j] = labels[j0 + tx * 4 + j];
  float ls = 0.f;
#pragma unroll
  for (int i = 0; i < 4; ++i)
#pragma unroll
    for (int j = 0; j < 4; ++j) {
      float s = acc[i][j];
      float x = (li[i] == lj[j]) ? (-10.f * (s - 0.6f)) : (40.f * (s - 0.4f));
      ls += log1pf(__expf(x));
    }
  float tot = blk_sum256(ls, sb);
  if (tid == 0) atomicAdd(&accbuf[1], tot);
}

// ---------- picked-label logits + feature-distance per row ----------
__global__ __launch_bounds__(256) void picked_k(const float* __restrict__ vn,
                                                const float* __restrict__ tn,
                                                const float* __restrict__ Wn,
                                                const float* __restrict__ Wtn,
                                                const int* __restrict__ labels,
                                                float* __restrict__ pv, float* __restrict__ pt,
                                                float* __restrict__ pf, float* __restrict__ df) {
  __shared__ float sb[4];
  int r = blockIdx.x;
  int lab = labels[r];
  float spv = 0.f, spt = 0.f, spf = 0.f, sdf = 0.f;
  for (int k = threadIdx.x; k < Dn; k += 256) {
    float a = vn[(size_t)r * Dn + k];
    float b = tn[(size_t)r * Dn + k];
    float w = Wn[(size_t)k * Cn + lab];
    float wt = Wtn[(size_t)k * Cn + lab];
    spv += a * w;
    spt += b * w;
    spf += b * wt;
    float dd = a - b;
    sdf += dd * dd;
  }
  spv = blk_sum256(spv, sb);
  spt = blk_sum256(spt, sb);
  spf = blk_sum256(spf, sb);
  sdf = blk_sum256(sdf, sb);
  if (threadIdx.x == 0) {
    pv[r] = 28.f * spv;
    pt[r] = 28.f * spt;
    pf[r] = 28.f * spf;
    df[r] = sdf;
  }
}

// ---------- reduce partials + per-row CE/KL/dist, accumulate acc[0] ----------
__global__ __launch_bounds__(256) void finalize_k(const float* __restrict__ part,
                                                  const float* __restrict__ pv,
                                                  const float* __restrict__ pt,
                                                  const float* __restrict__ pf,
                                                  const float* __restrict__ df,
                                                  float* __restrict__ accbuf) {
  __shared__ float sb[4];
  int r = blockIdx.x * 256 + threadIdx.x;
  float s[NQ];
#pragma unroll
  for (int q = 0; q < NQ; ++q) s[q] = 0.f;
  for (int ct = 0; ct < NCT; ++ct) {
#pragma unroll
    for (int q = 0; q < NQ; ++q)
      s[q] += part[(size_t)q * ((size_t)NCT * Bn) + (size_t)ct * Bn + r];
  }
  float lseV = logf(s[0]) + 28.f;
  float lseT = logf(s[2]) + 28.f;
  float lseF = logf(s[4]) + 28.f;
  const float invC = 1.f / (float)Cn;
  float ceV = -(0.9f * (pv[r] - lseV) + 0.1f * invC * (s[1] - (float)Cn * lseV));
  float ceT = -(0.9f * (pt[r] - lseT) + 0.1f * invC * (s[3] - (float)Cn * lseT));
  float ceF = -(0.9f * (pf[r] - lseF) + 0.1f * invC * (s[5] - (float)Cn * lseF));
  float kl = s[8] / (4.f * s[6]) + logf(s[7]) - logf(s[6]);
  float row = ceV + ceT + ceF + kl + df[r];
  float tot = blk_sum256(row, sb);
  if (threadIdx.x == 0) atomicAdd(&accbuf[0], tot / (float)Bn);
}

// ---------- HardDarkRank: top-63 teacher neighbors, student suffix-LSE ----------
__global__ __launch_bounds__(256) void hdr_k(const float* __restrict__ Gv,
                                             const float* __restrict__ tn,
                                             const float* __restrict__ sqv,
                                             const float* __restrict__ sqt,
                                             float* __restrict__ accbuf) {
  __shared__ float key[Bn];   // teacher d^2 (ascending d^2 == descending score)
  __shared__ float ti[Dn];
  __shared__ float rv[256];
  __shared__ int ri[256];
  __shared__ int selIdx[64];
  __shared__ float selS[64];
  __shared__ float sb[4];
  const int i = blockIdx.x, tid = threadIdx.x;
  const float INF = __builtin_inff();
  float sqi = sqv[i];
  for (int j = tid; j < Bn; j += 256) {
    float d2 = sqi + sqv[j] - 2.f * Gv[(size_t)i * Bn + j];
    key[j] = (j == i) ? INF : fmaxf(d2, 1e-12f);
  }
  for (int k = tid; k < Dn; k += 256) ti[k] = tn[(size_t)i * Dn + k];
  __syncthreads();

  for (int it = 0; it < 63; ++it) {
    float bv = INF;
    int bi = Bn;
    for (int j = tid; j < Bn; j += 256) {
      float v = key[j];
      if (v < bv) { bv = v; bi = j; }  // strict: equal keeps earlier (smaller j)
    }
    rv[tid] = bv;
    ri[tid] = bi;
    __syncthreads();
    for (int sdist = 128; sdist > 0; sdist >>= 1) {
      if (tid < sdist) {
        float ov = rv[tid + sdist];
        int oi = ri[tid + sdist];
        if (ov < rv[tid] || (ov == rv[tid] && oi < ri[tid])) {
          rv[tid] = ov;
          ri[tid] = oi;
        }
      }
      __syncthreads();
    }
    if (tid == 0) {
      selIdx[it] = ri[0];
      key[ri[0]] = INF;
    }
    __syncthreads();
  }

  // student scores at the selected (teacher-ordered) indices
  for (int it = 0; it < 63; ++it) {
    int j = selIdx[it];
    float p = 0.f;
    for (int k = tid; k < Dn; k += 256) p += ti[k] * tn[(size_t)j * Dn + k];
    p = blk_sum256(p, sb);
    if (tid == 0) {
      float d2 = fmaxf(sqt[i] + sqt[j] - 2.f * p, 1e-12f);
      float d = sqrtf(d2);
      selS[it] = -3.f * d * d * d;
    }
    __syncthreads();
  }

  if (tid == 0) {
    float lse = selS[62];
    float loss = 0.f;  // k=62 contributes lse_tail - s = 0
    for (int k = 61; k >= 0; --k) {
      float a = fmaxf(lse, selS[k]);
      lse = a + logf(__expf(lse - a) + __expf(selS[k] - a));
      loss += lse - selS[k];
    }
    atomicAdd(&accbuf[2], loss);
  }
}

__global__ void combine_k(const float* __restrict__ accbuf, float* __restrict__ out) {
  out[0] = accbuf[0] + (2.f / (float)Bn) * accbuf[1] + (0.1f / (float)Bn) * accbuf[2];
}

// ---------- launch ----------
extern "C" void kernel_launch(void* const* d_in, const int* in_sizes, int n_in,
                              void* d_out, int out_size, void* d_ws, size_t ws_size,
                              hipStream_t stream) {
  const float* ve = (const float*)d_in[0];
  const float* te = (const float*)d_in[1];
  const int* labels = (const int*)d_in[2];
  const float* W = (const float*)d_in[3];
  const float* Wt = (const float*)d_in[4];
  float* out = (float*)d_out;

  float* ws = (float*)d_ws;
  size_t off = 0;
  float* vn = ws + off;  off += (size_t)Bn * Dn;
  float* tn = ws + off;  off += (size_t)Bn * Dn;
  float* Wn = ws + off;  off += (size_t)Dn * Cn;
  float* Wtn = ws + off; off += (size_t)Dn * Cn;
  float* Gv = ws + off;  off += (size_t)Bn * Bn;
  float* part = ws + off; off += (size_t)NQ * NCT * Bn;
  float* sqv = ws + off; off += Bn;
  float* sqt = ws + off; off += Bn;
  float* pv = ws + off;  off += Bn;
  float* pt = ws + off;  off += Bn;
  float* pf = ws + off;  off += Bn;
  float* df = ws + off;  off += Bn;
  float* acc = ws + off; off += 8;

  zero_acc_k<<<1, 64, 0, stream>>>(acc);
  rownorm_k<<<Bn, 256, 0, stream>>>(ve, vn, sqv);
  rownorm_k<<<Bn, 256, 0, stream>>>(te, tn, sqt);
  colnorm_k<<<(Cn + 255) / 256, 256, 0, stream>>>(W, Wn);
  colnorm_k<<<(Cn + 255) / 256, 256, 0, stream>>>(Wt, Wtn);
  logits_k<<<dim3(NCT, Bn / 64), 256, 0, stream>>>(vn, tn, Wn, Wtn, part);
  gram_k<<<dim3(Bn / 64, Bn / 64), 256, 0, stream>>>(vn, vn, Gv);
  align_k<<<dim3(Bn / 64, Bn / 64), 256, 0, stream>>>(vn, tn, labels, acc);
  picked_k<<<Bn, 256, 0, stream>>>(vn, tn, Wn, Wtn, labels, pv, pt, pf, df);
  finalize_k<<<Bn / 256, 256, 0, stream>>>(part, pv, pt, pf, df, acc);
  hdr_k<<<Bn, 256, 0, stream>>>(Gv, tn, sqv, sqt, acc);
  combine_k<<<1, 1, 0, stream>>>(acc, out);
}

// Round 2
// 1452.980 us; speedup vs baseline: 4.2901x; 4.2901x over previous
//
#include <hip/hip_runtime.h>
#include <math.h>

#define Bn 4096
#define Dn 1024
#define Cn 11003
#define Cpad 11008
#define NCTL 86
#define NQ 9

typedef __attribute__((ext_vector_type(8))) short bf16x8;
typedef __attribute__((ext_vector_type(4))) float f32x4;

__device__ __forceinline__ unsigned short f2bf(float f) {
  union { float f; unsigned u; } v; v.f = f;
  unsigned r = (v.u + 0x7fffu + ((v.u >> 16) & 1u)) >> 16;
  return (unsigned short)r;
}
__device__ __forceinline__ float bf2f(unsigned short h) {
  union { unsigned u; float f; } v; v.u = ((unsigned)h) << 16;
  return v.f;
}

__device__ __forceinline__ void stage16(const unsigned short* g, unsigned short* l) {
  __builtin_amdgcn_global_load_lds(
      (const __attribute__((address_space(1))) void*)g,
      (__attribute__((address_space(3))) void*)l, 16, 0, 0);
}

__device__ __forceinline__ float blk_sum256(float v, volatile float* sb) {
#pragma unroll
  for (int o = 32; o > 0; o >>= 1) v += __shfl_down(v, o, 64);
  __syncthreads();
  if ((threadIdx.x & 63) == 0) sb[threadIdx.x >> 6] = v;
  __syncthreads();
  return sb[0] + sb[1] + sb[2] + sb[3];
}

__global__ void zero_acc_k(float* acc) {
  if (threadIdx.x < 8) acc[threadIdx.x] = 0.f;
}

// ---------- row L2 normalize: fp32 out + bf16 out + post-norm sumsq ----------
__global__ __launch_bounds__(256) void rownorm_k(const float* __restrict__ x,
                                                 float* __restrict__ y,
                                                 unsigned short* __restrict__ yh,
                                                 float* __restrict__ sq) {
  __shared__ float sb[4];
  int r = blockIdx.x;
  const float* xr = x + (size_t)r * Dn;
  float s = 0.f;
  for (int k = threadIdx.x; k < Dn; k += 256) { float v = xr[k]; s += v * v; }
  s = blk_sum256(s, sb);
  float nrm = sqrtf(s);
  float s2 = 0.f;
  for (int k = threadIdx.x; k < Dn; k += 256) {
    float v = xr[k] / nrm;
    y[(size_t)r * Dn + k] = v;
    yh[(size_t)r * Dn + k] = f2bf(v);
    s2 += v * v;
  }
  s2 = blk_sum256(s2, sb);
  if (threadIdx.x == 0) sq[r] = s2;
}

// ---------- column inverse-norms of W [Dn x Cn] ----------
__global__ __launch_bounds__(256) void colnorm_k(const float* __restrict__ W,
                                                 float* __restrict__ rn) {
  int c = blockIdx.x * 256 + threadIdx.x;
  if (c >= Cn) return;
  float s = 0.f;
  for (int d = 0; d < Dn; ++d) { float v = W[(size_t)d * Cn + c]; s += v * v; }
  rn[c] = 1.f / sqrtf(s);
}

// ---------- transpose+normalize+bf16: W [Dn x Cn] -> WT [Cpad x Dn] ----------
__global__ __launch_bounds__(256) void transpose_k(const float* __restrict__ W,
                                                   const float* __restrict__ rn,
                                                   unsigned short* __restrict__ WT) {
  __shared__ float T[64][65];
  const int c0 = blockIdx.x * 64, d0 = blockIdx.y * 64;
  const int tid = threadIdx.x;
  const int cl = tid & 63;
  for (int dl = tid >> 6; dl < 64; dl += 4) {
    float v = (c0 + cl < Cn) ? W[(size_t)(d0 + dl) * Cn + c0 + cl] : 0.f;
    T[cl][dl] = v;
  }
  __syncthreads();
  const int dd = tid & 63;
  for (int co = tid >> 6; co < 64; co += 4) {
    int c = c0 + co;
    unsigned short o = 0;
    if (c < Cn) o = f2bf(T[co][dd] * rn[c]);
    WT[(size_t)c * Dn + d0 + dd] = o;
  }
}

// ---------- dual logits GEMM (V = vn@Wn, T = tn@Wn) + 7 row quantities ----------
__global__ __launch_bounds__(256, 2) void logits_vt_k(
    const unsigned short* __restrict__ vnh, const unsigned short* __restrict__ tnh,
    const unsigned short* __restrict__ WnT, float* __restrict__ part) {
  __shared__ __align__(16) unsigned short Av[128 * 64];
  __shared__ __align__(16) unsigned short At[128 * 64];
  __shared__ __align__(16) unsigned short Bs[128 * 64];
  __shared__ float qsum[7 * 128];

  const int rt = blockIdx.x, ct = blockIdx.y;
  const int r0 = rt * 128, c0 = ct * 128;
  const int tid = threadIdx.x;
  const int lane = tid & 63;
  const int wid = tid >> 6;
  const int wr = (wid >> 1) * 64, wc = (wid & 1) * 64;
  const int m = lane & 15, q = lane >> 4;

  for (int t = tid; t < 7 * 128; t += 256) qsum[t] = 0.f;

  const f32x4 zero4 = {0.f, 0.f, 0.f, 0.f};
  f32x4 accV[4][4], accT[4][4];
#pragma unroll
  for (int i = 0; i < 4; ++i)
#pragma unroll
    for (int j = 0; j < 4; ++j) { accV[i][j] = zero4; accT[i][j] = zero4; }

  const int srow = tid >> 3;
  const int skc = (tid & 7) * 8;

  for (int kk = 0; kk < 16; ++kk) {
    const int k0 = kk * 64;
#pragma unroll
    for (int p = 0; p < 4; ++p) {
      stage16(vnh + (size_t)(r0 + p * 32 + srow) * Dn + k0 + skc, Av + p * 2048 + tid * 8);
      stage16(tnh + (size_t)(r0 + p * 32 + srow) * Dn + k0 + skc, At + p * 2048 + tid * 8);
      stage16(WnT + (size_t)(c0 + p * 32 + srow) * Dn + k0 + skc, Bs + p * 2048 + tid * 8);
    }
    __syncthreads();
#pragma unroll
    for (int ks = 0; ks < 2; ++ks) {
      bf16x8 av[4], at[4], bb[4];
#pragma unroll
      for (int f = 0; f < 4; ++f) {
        av[f] = *(const bf16x8*)(Av + (wr + f * 16 + m) * 64 + ks * 32 + q * 8);
        at[f] = *(const bf16x8*)(At + (wr + f * 16 + m) * 64 + ks * 32 + q * 8);
        bb[f] = *(const bf16x8*)(Bs + (wc + f * 16 + m) * 64 + ks * 32 + q * 8);
      }
#pragma unroll
      for (int i = 0; i < 4; ++i)
#pragma unroll
        for (int j = 0; j < 4; ++j) {
          accV[i][j] = __builtin_amdgcn_mfma_f32_16x16x32_bf16(av[i], bb[j], accV[i][j], 0, 0, 0);
          accT[i][j] = __builtin_amdgcn_mfma_f32_16x16x32_bf16(at[i], bb[j], accT[i][j], 0, 0, 0);
        }
    }
    __syncthreads();
  }

  // epilogue: quantities q0,q1,q2,q3,q6,q7,q8 (slots 0..6)
#pragma unroll
  for (int i = 0; i < 4; ++i) {
#pragma unroll
    for (int r = 0; r < 4; ++r) {
      const int rowl = wr + i * 16 + q * 4 + r;
      float s0 = 0.f, s1 = 0.f, s2 = 0.f, s3 = 0.f, s6 = 0.f, s7 = 0.f, s8 = 0.f;
#pragma unroll
      for (int j = 0; j < 4; ++j) {
        int col = c0 + wc + j * 16 + m;
        if (col < Cn) {
          float V = 28.f * accV[i][j][r];
          float T = 28.f * accT[i][j][r];
          float ev4 = __expf((V - 28.f) * 0.25f);
          float et4 = __expf((T - 28.f) * 0.25f);
          float ev2 = ev4 * ev4, et2 = et4 * et4;
          s0 += ev2 * ev2;
          s1 += V;
          s2 += et2 * et2;
          s3 += T;
          s6 += ev4;
          s7 += et4;
          s8 += ev4 * (V - T);
        }
      }
#pragma unroll
      for (int o = 1; o < 16; o <<= 1) {
        s0 += __shfl_xor(s0, o, 64); s1 += __shfl_xor(s1, o, 64);
        s2 += __shfl_xor(s2, o, 64); s3 += __shfl_xor(s3, o, 64);
        s6 += __shfl_xor(s6, o, 64); s7 += __shfl_xor(s7, o, 64);
        s8 += __shfl_xor(s8, o, 64);
      }
      if (m == 0) {
        atomicAdd(&qsum[0 * 128 + rowl], s0);
        atomicAdd(&qsum[1 * 128 + rowl], s1);
        atomicAdd(&qsum[2 * 128 + rowl], s2);
        atomicAdd(&qsum[3 * 128 + rowl], s3);
        atomicAdd(&qsum[4 * 128 + rowl], s6);
        atomicAdd(&qsum[5 * 128 + rowl], s7);
        atomicAdd(&qsum[6 * 128 + rowl], s8);
      }
    }
  }
  __syncthreads();
  if (tid < 128) {
    size_t base = (size_t)ct * Bn + r0 + tid;
    const size_t qs = (size_t)NCTL * Bn;
    part[0 * qs + base] = qsum[0 * 128 + tid];
    part[1 * qs + base] = qsum[1 * 128 + tid];
    part[2 * qs + base] = qsum[2 * 128 + tid];
    part[3 * qs + base] = qsum[3 * 128 + tid];
    part[6 * qs + base] = qsum[4 * 128 + tid];
    part[7 * qs + base] = qsum[5 * 128 + tid];
    part[8 * qs + base] = qsum[6 * 128 + tid];
  }
}

// ---------- filter logits GEMM (F = tn@Wtn) + 2 row quantities ----------
__global__ __launch_bounds__(256, 2) void logits_f_k(
    const unsigned short* __restrict__ tnh, const unsigned short* __restrict__ WtnT,
    float* __restrict__ part) {
  __shared__ __align__(16) unsigned short Aa[128 * 64];
  __shared__ __align__(16) unsigned short Bs[128 * 64];
  __shared__ float qsum[2 * 128];

  const int rt = blockIdx.x, ct = blockIdx.y;
  const int r0 = rt * 128, c0 = ct * 128;
  const int tid = threadIdx.x;
  const int lane = tid & 63;
  const int wid = tid >> 6;
  const int wr = (wid >> 1) * 64, wc = (wid & 1) * 64;
  const int m = lane & 15, q = lane >> 4;

  for (int t = tid; t < 2 * 128; t += 256) qsum[t] = 0.f;

  const f32x4 zero4 = {0.f, 0.f, 0.f, 0.f};
  f32x4 acc[4][4];
#pragma unroll
  for (int i = 0; i < 4; ++i)
#pragma unroll
    for (int j = 0; j < 4; ++j) acc[i][j] = zero4;

  const int srow = tid >> 3;
  const int skc = (tid & 7) * 8;

  for (int kk = 0; kk < 16; ++kk) {
    const int k0 = kk * 64;
#pragma unroll
    for (int p = 0; p < 4; ++p) {
      stage16(tnh + (size_t)(r0 + p * 32 + srow) * Dn + k0 + skc, Aa + p * 2048 + tid * 8);
      stage16(WtnT + (size_t)(c0 + p * 32 + srow) * Dn + k0 + skc, Bs + p * 2048 + tid * 8);
    }
    __syncthreads();
#pragma unroll
    for (int ks = 0; ks < 2; ++ks) {
      bf16x8 aa[4], bb[4];
#pragma unroll
      for (int f = 0; f < 4; ++f) {
        aa[f] = *(const bf16x8*)(Aa + (wr + f * 16 + m) * 64 + ks * 32 + q * 8);
        bb[f] = *(const bf16x8*)(Bs + (wc + f * 16 + m) * 64 + ks * 32 + q * 8);
      }
#pragma unroll
      for (int i = 0; i < 4; ++i)
#pragma unroll
        for (int j = 0; j < 4; ++j)
          acc[i][j] = __builtin_amdgcn_mfma_f32_16x16x32_bf16(aa[i], bb[j], acc[i][j], 0, 0, 0);
    }
    __syncthreads();
  }

#pragma unroll
  for (int i = 0; i < 4; ++i) {
#pragma unroll
    for (int r = 0; r < 4; ++r) {
      const int rowl = wr + i * 16 + q * 4 + r;
      float s4 = 0.f, s5 = 0.f;
#pragma unroll
      for (int j = 0; j < 4; ++j) {
        int col = c0 + wc + j * 16 + m;
        if (col < Cn) {
          float F = 28.f * acc[i][j][r];
          s4 += __expf(F - 28.f);
          s5 += F;
        }
      }
#pragma unroll
      for (int o = 1; o < 16; o <<= 1) {
        s4 += __shfl_xor(s4, o, 64);
        s5 += __shfl_xor(s5, o, 64);
      }
      if (m == 0) {
        atomicAdd(&qsum[0 * 128 + rowl], s4);
        atomicAdd(&qsum[1 * 128 + rowl], s5);
      }
    }
  }
  __syncthreads();
  if (tid < 128) {
    size_t base = (size_t)ct * Bn + r0 + tid;
    const size_t qs = (size_t)NCTL * Bn;
    part[4 * qs + base] = qsum[0 * 128 + tid];
    part[5 * qs + base] = qsum[1 * 128 + tid];
  }
}

// ---------- gram GEMM: Gv = vnh @ vnh^T (fp32 out) ----------
__global__ __launch_bounds__(256, 2) void gram_k(const unsigned short* __restrict__ A,
                                                 const unsigned short* __restrict__ Bm,
                                                 float* __restrict__ G) {
  __shared__ __align__(16) unsigned short Aa[128 * 64];
  __shared__ __align__(16) unsigned short Bs[128 * 64];
  const int jt = blockIdx.x, it = blockIdx.y;
  const int j0 = jt * 128, i0 = it * 128;
  const int tid = threadIdx.x;
  const int lane = tid & 63;
  const int wid = tid >> 6;
  const int wr = (wid >> 1) * 64, wc = (wid & 1) * 64;
  const int m = lane & 15, q = lane >> 4;

  const f32x4 zero4 = {0.f, 0.f, 0.f, 0.f};
  f32x4 acc[4][4];
#pragma unroll
  for (int i = 0; i < 4; ++i)
#pragma unroll
    for (int j = 0; j < 4; ++j) acc[i][j] = zero4;

  const int srow = tid >> 3;
  const int skc = (tid & 7) * 8;

  for (int kk = 0; kk < 16; ++kk) {
    const int k0 = kk * 64;
#pragma unroll
    for (int p = 0; p < 4; ++p) {
      stage16(A + (size_t)(i0 + p * 32 + srow) * Dn + k0 + skc, Aa + p * 2048 + tid * 8);
      stage16(Bm + (size_t)(j0 + p * 32 + srow) * Dn + k0 + skc, Bs + p * 2048 + tid * 8);
    }
    __syncthreads();
#pragma unroll
    for (int ks = 0; ks < 2; ++ks) {
      bf16x8 aa[4], bb[4];
#pragma unroll
      for (int f = 0; f < 4; ++f) {
        aa[f] = *(const bf16x8*)(Aa + (wr + f * 16 + m) * 64 + ks * 32 + q * 8);
        bb[f] = *(const bf16x8*)(Bs + (wc + f * 16 + m) * 64 + ks * 32 + q * 8);
      }
#pragma unroll
      for (int i = 0; i < 4; ++i)
#pragma unroll
        for (int j = 0; j < 4; ++j)
          acc[i][j] = __builtin_amdgcn_mfma_f32_16x16x32_bf16(aa[i], bb[j], acc[i][j], 0, 0, 0);
    }
    __syncthreads();
  }
#pragma unroll
  for (int i = 0; i < 4; ++i)
#pragma unroll
    for (int j = 0; j < 4; ++j)
#pragma unroll
      for (int r = 0; r < 4; ++r)
        G[(size_t)(i0 + wr + i * 16 + q * 4 + r) * Bn + j0 + wc + j * 16 + m] = acc[i][j][r];
}

// ---------- global-align GEMM: sim = vnh @ tnh^T fused loss ----------
__global__ __launch_bounds__(256, 2) void align_k(const unsigned short* __restrict__ vnh,
                                                  const unsigned short* __restrict__ tnh,
                                                  const int* __restrict__ labels,
                                                  float* __restrict__ accbuf) {
  __shared__ __align__(16) unsigned short Aa[128 * 64];
  __shared__ __align__(16) unsigned short Bs[128 * 64];
  __shared__ int li_s[128], lj_s[128];
  __shared__ float sb[4];
  const int jt = blockIdx.x, it = blockIdx.y;
  const int j0 = jt * 128, i0 = it * 128;
  const int tid = threadIdx.x;
  const int lane = tid & 63;
  const int wid = tid >> 6;
  const int wr = (wid >> 1) * 64, wc = (wid & 1) * 64;
  const int m = lane & 15, q = lane >> 4;

  if (tid < 128) li_s[tid] = labels[i0 + tid];
  else lj_s[tid - 128] = labels[j0 + tid - 128];

  const f32x4 zero4 = {0.f, 0.f, 0.f, 0.f};
  f32x4 acc[4][4];
#pragma unroll
  for (int i = 0; i < 4; ++i)
#pragma unroll
    for (int j = 0; j < 4; ++j) acc[i][j] = zero4;

  const int srow = tid >> 3;
  const int skc = (tid & 7) * 8;

  for (int kk = 0; kk < 16; ++kk) {
    const int k0 = kk * 64;
#pragma unroll
    for (int p = 0; p < 4; ++p) {
      stage16(vnh + (size_t)(i0 + p * 32 + srow) * Dn + k0 + skc, Aa + p * 2048 + tid * 8);
      stage16(tnh + (size_t)(j0 + p * 32 + srow) * Dn + k0 + skc, Bs + p * 2048 + tid * 8);
    }
    __syncthreads();
#pragma unroll
    for (int ks = 0; ks < 2; ++ks) {
      bf16x8 aa[4], bb[4];
#pragma unroll
      for (int f = 0; f < 4; ++f) {
        aa[f] = *(const bf16x8*)(Aa + (wr + f * 16 + m) * 64 + ks * 32 + q * 8);
        bb[f] = *(const bf16x8*)(Bs + (wc + f * 16 + m) * 64 + ks * 32 + q * 8);
      }
#pragma unroll
      for (int i = 0; i < 4; ++i)
#pragma unroll
        for (int j = 0; j < 4; ++j)
          acc[i][j] = __builtin_amdgcn_mfma_f32_16x16x32_bf16(aa[i], bb[j], acc[i][j], 0, 0, 0);
    }
    __syncthreads();
  }

  float ls = 0.f;
#pragma unroll
  for (int i = 0; i < 4; ++i)
#pragma unroll
    for (int r = 0; r < 4; ++r) {
      int li = li_s[wr + i * 16 + q * 4 + r];
#pragma unroll
      for (int j = 0; j < 4; ++j) {
        int lj = lj_s[wc + j * 16 + m];
        float s = acc[i][j][r];
        float x = (li == lj) ? (-10.f * (s - 0.6f)) : (40.f * (s - 0.4f));
        // log1p(exp(x)) = max(x,0) + log(1+exp(-|x|))
        ls += fmaxf(x, 0.f) + __logf(1.f + __expf(-fabsf(x)));
      }
    }
  float tot = blk_sum256(ls, sb);
  if (tid == 0) atomicAdd(&accbuf[1], tot);
}

// ---------- picked-label logits + feature-distance per row ----------
__global__ __launch_bounds__(256) void picked_k(const float* __restrict__ vn,
                                                const float* __restrict__ tn,
                                                const unsigned short* __restrict__ WnT,
                                                const unsigned short* __restrict__ WtnT,
                                                const int* __restrict__ labels,
                                                float* __restrict__ pv, float* __restrict__ pt,
                                                float* __restrict__ pf, float* __restrict__ df) {
  __shared__ float sb[4];
  int r = blockIdx.x;
  int lab = labels[r];
  float spv = 0.f, spt = 0.f, spf = 0.f, sdf = 0.f;
  for (int k = threadIdx.x; k < Dn; k += 256) {
    float a = vn[(size_t)r * Dn + k];
    float b = tn[(size_t)r * Dn + k];
    float w = bf2f(WnT[(size_t)lab * Dn + k]);
    float wt = bf2f(WtnT[(size_t)lab * Dn + k]);
    spv += a * w;
    spt += b * w;
    spf += b * wt;
    float dd = a - b;
    sdf += dd * dd;
  }
  spv = blk_sum256(spv, sb);
  spt = blk_sum256(spt, sb);
  spf = blk_sum256(spf, sb);
  sdf = blk_sum256(sdf, sb);
  if (threadIdx.x == 0) {
    pv[r] = 28.f * spv;
    pt[r] = 28.f * spt;
    pf[r] = 28.f * spf;
    df[r] = sdf;
  }
}

// ---------- reduce partials + per-row CE/KL/dist ----------
__global__ __launch_bounds__(256) void finalize_k(const float* __restrict__ part,
                                                  const float* __restrict__ pv,
                                                  const float* __restrict__ pt,
                                                  const float* __restrict__ pf,
                                                  const float* __restrict__ df,
                                                  float* __restrict__ accbuf) {
  __shared__ float sb[4];
  int r = blockIdx.x * 256 + threadIdx.x;
  float s[NQ];
#pragma unroll
  for (int q = 0; q < NQ; ++q) s[q] = 0.f;
  const size_t qs = (size_t)NCTL * Bn;
  for (int ct = 0; ct < NCTL; ++ct) {
#pragma unroll
    for (int q = 0; q < NQ; ++q) s[q] += part[(size_t)q * qs + (size_t)ct * Bn + r];
  }
  float lseV = logf(s[0]) + 28.f;
  float lseT = logf(s[2]) + 28.f;
  float lseF = logf(s[4]) + 28.f;
  const float invC = 1.f / (float)Cn;
  float ceV = -(0.9f * (pv[r] - lseV) + 0.1f * invC * (s[1] - (float)Cn * lseV));
  float ceT = -(0.9f * (pt[r] - lseT) + 0.1f * invC * (s[3] - (float)Cn * lseT));
  float ceF = -(0.9f * (pf[r] - lseF) + 0.1f * invC * (s[5] - (float)Cn * lseF));
  float kl = s[8] / (4.f * s[6]) + logf(s[7]) - logf(s[6]);
  float row = ceV + ceT + ceF + kl + df[r];
  float tot = blk_sum256(row, sb);
  if (threadIdx.x == 0) atomicAdd(&accbuf[0], tot / (float)Bn);
}

// ---------- HardDarkRank ----------
__global__ __launch_bounds__(256) void hdr_k(const float* __restrict__ Gv,
                                             const float* __restrict__ tn,
                                             const float* __restrict__ sqv,
                                             const float* __restrict__ sqt,
                                             float* __restrict__ accbuf) {
  __shared__ float key[Bn];
  __shared__ float ti[Dn];
  __shared__ int selIdx[63];
  __shared__ float selS[63];
  const int i = blockIdx.x, tid = threadIdx.x;
  const int lane = tid & 63, wid = tid >> 6;
  const float INF = __builtin_inff();
  float sqi = sqv[i];
  for (int j = tid; j < Bn; j += 256) {
    float d2 = sqi + sqv[j] - 2.f * Gv[(size_t)i * Bn + j];
    key[j] = (j == i) ? INF : fmaxf(d2, 1e-12f);
  }
  for (int k = tid; k < Dn; k += 256) ti[k] = tn[(size_t)i * Dn + k];
  __syncthreads();

  if (wid == 0) {
    // per-lane register segment minimum (segment = 64 keys)
    float mn = INF;
    for (int k = 0; k < 64; ++k) mn = fminf(mn, key[lane * 64 + k]);
    for (int it = 0; it < 63; ++it) {
      // 1) winning segment (tie -> smaller segment)
      float v = mn; int bseg = lane;
#pragma unroll
      for (int o = 32; o > 0; o >>= 1) {
        float ov = __shfl_xor(v, o, 64); int oi = __shfl_xor(bseg, o, 64);
        if (ov < v || (ov == v && oi < bseg)) { v = ov; bseg = oi; }
      }
      // 2) exact index within segment (tie -> smaller j)
      float kv = key[bseg * 64 + lane];
      float v2 = kv; int bj = bseg * 64 + lane;
#pragma unroll
      for (int o = 32; o > 0; o >>= 1) {
        float ov = __shfl_xor(v2, o, 64); int oi = __shfl_xor(bj, o, 64);
        if (ov < v2 || (ov == v2 && oi < bj)) { v2 = ov; bj = oi; }
      }
      if (lane == (bj & 63)) key[bj] = INF;
      if (lane == 0) selIdx[it] = bj;
      // 3) refresh that segment's register min
      float kv3 = (lane == (bj & 63)) ? INF : kv;
#pragma unroll
      for (int o = 32; o > 0; o >>= 1) kv3 = fminf(kv3, __shfl_xor(kv3, o, 64));
      if (lane == bseg) mn = kv3;
    }
  }
  __syncthreads();

  float sqti = sqt[i];
  for (int it = wid; it < 63; it += 4) {
    int j = selIdx[it];
    float p = 0.f;
    for (int k = lane; k < Dn; k += 64) p += ti[k] * tn[(size_t)j * Dn + k];
#pragma unroll
    for (int o = 32; o > 0; o >>= 1) p += __shfl_xor(p, o, 64);
    if (lane == 0) {
      float d2 = fmaxf(sqti + sqt[j] - 2.f * p, 1e-12f);
      float d = sqrtf(d2);
      selS[it] = -3.f * d * d2;
    }
  }
  __syncthreads();

  if (tid == 0) {
    float lse = selS[62];
    float loss = 0.f;
    for (int k = 61; k >= 0; --k) {
      float a = fmaxf(lse, selS[k]);
      lse = a + logf(__expf(lse - a) + __expf(selS[k] - a));
      loss += lse - selS[k];
    }
    atomicAdd(&accbuf[2], loss);
  }
}

__global__ void combine_k(const float* __restrict__ accbuf, float* __restrict__ out) {
  out[0] = accbuf[0] + (2.f / (float)Bn) * accbuf[1] + (0.1f / (float)Bn) * accbuf[2];
}

// ---------- launch ----------
extern "C" void kernel_launch(void* const* d_in, const int* in_sizes, int n_in,
                              void* d_out, int out_size, void* d_ws, size_t ws_size,
                              hipStream_t stream) {
  const float* ve = (const float*)d_in[0];
  const float* te = (const float*)d_in[1];
  const int* labels = (const int*)d_in[2];
  const float* W = (const float*)d_in[3];
  const float* Wt = (const float*)d_in[4];
  float* out = (float*)d_out;

  float* ws = (float*)d_ws;
  size_t off = 0;
  float* vn = ws + off;   off += (size_t)Bn * Dn;
  float* tn = ws + off;   off += (size_t)Bn * Dn;
  float* Gv = ws + off;   off += (size_t)Bn * Bn;
  float* part = ws + off; off += (size_t)NQ * NCTL * Bn;
  unsigned short* vnh = (unsigned short*)(ws + off);  off += (size_t)Bn * Dn / 2;
  unsigned short* tnh = (unsigned short*)(ws + off);  off += (size_t)Bn * Dn / 2;
  unsigned short* WnT = (unsigned short*)(ws + off);  off += (size_t)Cpad * Dn / 2;
  unsigned short* WtnT = (unsigned short*)(ws + off); off += (size_t)Cpad * Dn / 2;
  float* rnW = ws + off;  off += Cpad;
  float* rnWt = ws + off; off += Cpad;
  float* sqv = ws + off;  off += Bn;
  float* sqt = ws + off;  off += Bn;
  float* pv = ws + off;   off += Bn;
  float* pt = ws + off;   off += Bn;
  float* pf = ws + off;   off += Bn;
  float* df = ws + off;   off += Bn;
  float* acc = ws + off;  off += 8;

  zero_acc_k<<<1, 64, 0, stream>>>(acc);
  rownorm_k<<<Bn, 256, 0, stream>>>(ve, vn, vnh, sqv);
  rownorm_k<<<Bn, 256, 0, stream>>>(te, tn, tnh, sqt);
  colnorm_k<<<(Cn + 255) / 256, 256, 0, stream>>>(W, rnW);
  colnorm_k<<<(Cn + 255) / 256, 256, 0, stream>>>(Wt, rnWt);
  transpose_k<<<dim3(Cpad / 64, Dn / 64), 256, 0, stream>>>(W, rnW, WnT);
  transpose_k<<<dim3(Cpad / 64, Dn / 64), 256, 0, stream>>>(Wt, rnWt, WtnT);
  logits_vt_k<<<dim3(Bn / 128, NCTL), 256, 0, stream>>>(vnh, tnh, WnT, part);
  logits_f_k<<<dim3(Bn / 128, NCTL), 256, 0, stream>>>(tnh, WtnT, part);
  gram_k<<<dim3(Bn / 128, Bn / 128), 256, 0, stream>>>(vnh, vnh, Gv);
  align_k<<<dim3(Bn / 128, Bn / 128), 256, 0, stream>>>(vnh, tnh, labels, acc);
  picked_k<<<Bn, 256, 0, stream>>>(vn, tn, WnT, WtnT, labels, pv, pt, pf, df);
  finalize_k<<<Bn / 256, 256, 0, stream>>>(part, pv, pt, pf, df, acc);
  hdr_k<<<Bn, 256, 0, stream>>>(Gv, tn, sqv, sqt, acc);
  combine_k<<<1, 1, 0, stream>>>(acc, out);
}

// Round 3
// 1072.522 us; speedup vs baseline: 5.8119x; 1.3547x over previous
//
#include <hip/hip_runtime.h>
#include <math.h>

#define Bn 4096
#define Dn 1024
#define Cn 11003
#define Cpad 11008
#define NCTL 86
#define NQ 9
#define NT 32
#define NTRI 528  // NT*(NT+1)/2

typedef __attribute__((ext_vector_type(8))) short bf16x8;
typedef __attribute__((ext_vector_type(4))) float f32x4;

__device__ __forceinline__ unsigned short f2bf(float f) {
  union { float f; unsigned u; } v; v.f = f;
  unsigned r = (v.u + 0x7fffu + ((v.u >> 16) & 1u)) >> 16;
  return (unsigned short)r;
}
__device__ __forceinline__ float bf2f(unsigned short h) {
  union { unsigned u; float f; } v; v.u = ((unsigned)h) << 16;
  return v.f;
}

__device__ __forceinline__ void stage16(const unsigned short* g, unsigned short* l) {
  __builtin_amdgcn_global_load_lds(
      (const __attribute__((address_space(1))) void*)g,
      (__attribute__((address_space(3))) void*)l, 16, 0, 0);
}

__device__ __forceinline__ float blk_sum256(float v, volatile float* sb) {
#pragma unroll
  for (int o = 32; o > 0; o >>= 1) v += __shfl_down(v, o, 64);
  __syncthreads();
  if ((threadIdx.x & 63) == 0) sb[threadIdx.x >> 6] = v;
  __syncthreads();
  return sb[0] + sb[1] + sb[2] + sb[3];
}

__global__ void zero_acc_k(float* acc) {
  if (threadIdx.x < 8) acc[threadIdx.x] = 0.f;
}

// ---------- row L2 normalize -> bf16 + post-norm sumsq ----------
__global__ __launch_bounds__(256) void rownorm_k(const float* __restrict__ x,
                                                 unsigned short* __restrict__ yh,
                                                 float* __restrict__ sq) {
  __shared__ float sb[4];
  int r = blockIdx.x;
  const float* xr = x + (size_t)r * Dn;
  float s = 0.f;
  for (int k = threadIdx.x; k < Dn; k += 256) { float v = xr[k]; s += v * v; }
  s = blk_sum256(s, sb);
  float nrm = sqrtf(s);
  float s2 = 0.f;
  for (int k = threadIdx.x; k < Dn; k += 256) {
    float v = xr[k] / nrm;
    yh[(size_t)r * Dn + k] = f2bf(v);
    s2 += v * v;
  }
  s2 = blk_sum256(s2, sb);
  if (threadIdx.x == 0) sq[r] = s2;
}

// ---------- column inverse-norms of W [Dn x Cn] ----------
__global__ __launch_bounds__(256) void colnorm_k(const float* __restrict__ W,
                                                 float* __restrict__ rn) {
  int c = blockIdx.x * 256 + threadIdx.x;
  if (c >= Cn) return;
  float s = 0.f;
  for (int d = 0; d < Dn; ++d) { float v = W[(size_t)d * Cn + c]; s += v * v; }
  rn[c] = 1.f / sqrtf(s);
}

// ---------- transpose+normalize+bf16: W [Dn x Cn] -> WT [Cpad x Dn] ----------
__global__ __launch_bounds__(256) void transpose_k(const float* __restrict__ W,
                                                   const float* __restrict__ rn,
                                                   unsigned short* __restrict__ WT) {
  __shared__ float T[64][65];
  const int c0 = blockIdx.x * 64, d0 = blockIdx.y * 64;
  const int tid = threadIdx.x;
  const int cl = tid & 63;
  for (int dl = tid >> 6; dl < 64; dl += 4) {
    float v = (c0 + cl < Cn) ? W[(size_t)(d0 + dl) * Cn + c0 + cl] : 0.f;
    T[cl][dl] = v;
  }
  __syncthreads();
  const int dd = tid & 63;
  for (int co = tid >> 6; co < 64; co += 4) {
    int c = c0 + co;
    unsigned short o = 0;
    if (c < Cn) o = f2bf(T[co][dd] * rn[c]);
    WT[(size_t)c * Dn + d0 + dd] = o;
  }
}

// ---------- dual logits GEMM (V = vn@Wn, T = tn@Wn) + 7 row quantities ----------
__global__ __launch_bounds__(256, 2) void logits_vt_k(
    const unsigned short* __restrict__ vnh, const unsigned short* __restrict__ tnh,
    const unsigned short* __restrict__ WnT, float* __restrict__ part) {
  __shared__ __align__(16) unsigned short Av[128 * 64];
  __shared__ __align__(16) unsigned short At[128 * 64];
  __shared__ __align__(16) unsigned short Bs[128 * 64];
  __shared__ float qsum[7 * 128];

  const int rt = blockIdx.x, ct = blockIdx.y;
  const int r0 = rt * 128, c0 = ct * 128;
  const int tid = threadIdx.x;
  const int lane = tid & 63;
  const int wid = tid >> 6;
  const int wr = (wid >> 1) * 64, wc = (wid & 1) * 64;
  const int m = lane & 15, q = lane >> 4;

  for (int t = tid; t < 7 * 128; t += 256) qsum[t] = 0.f;

  const f32x4 zero4 = {0.f, 0.f, 0.f, 0.f};
  f32x4 accV[4][4], accT[4][4];
#pragma unroll
  for (int i = 0; i < 4; ++i)
#pragma unroll
    for (int j = 0; j < 4; ++j) { accV[i][j] = zero4; accT[i][j] = zero4; }

  const int srow = tid >> 3;
  const int skc = (tid & 7) * 8;

  for (int kk = 0; kk < 16; ++kk) {
    const int k0 = kk * 64;
#pragma unroll
    for (int p = 0; p < 4; ++p) {
      stage16(vnh + (size_t)(r0 + p * 32 + srow) * Dn + k0 + skc, Av + p * 2048 + tid * 8);
      stage16(tnh + (size_t)(r0 + p * 32 + srow) * Dn + k0 + skc, At + p * 2048 + tid * 8);
      stage16(WnT + (size_t)(c0 + p * 32 + srow) * Dn + k0 + skc, Bs + p * 2048 + tid * 8);
    }
    __syncthreads();
#pragma unroll
    for (int ks = 0; ks < 2; ++ks) {
      bf16x8 av[4], at[4], bb[4];
#pragma unroll
      for (int f = 0; f < 4; ++f) {
        av[f] = *(const bf16x8*)(Av + (wr + f * 16 + m) * 64 + ks * 32 + q * 8);
        at[f] = *(const bf16x8*)(At + (wr + f * 16 + m) * 64 + ks * 32 + q * 8);
        bb[f] = *(const bf16x8*)(Bs + (wc + f * 16 + m) * 64 + ks * 32 + q * 8);
      }
#pragma unroll
      for (int i = 0; i < 4; ++i)
#pragma unroll
        for (int j = 0; j < 4; ++j) {
          accV[i][j] = __builtin_amdgcn_mfma_f32_16x16x32_bf16(av[i], bb[j], accV[i][j], 0, 0, 0);
          accT[i][j] = __builtin_amdgcn_mfma_f32_16x16x32_bf16(at[i], bb[j], accT[i][j], 0, 0, 0);
        }
    }
    __syncthreads();
  }

#pragma unroll
  for (int i = 0; i < 4; ++i) {
#pragma unroll
    for (int r = 0; r < 4; ++r) {
      const int rowl = wr + i * 16 + q * 4 + r;
      float s0 = 0.f, s1 = 0.f, s2 = 0.f, s3 = 0.f, s6 = 0.f, s7 = 0.f, s8 = 0.f;
#pragma unroll
      for (int j = 0; j < 4; ++j) {
        int col = c0 + wc + j * 16 + m;
        if (col < Cn) {
          float V = 28.f * accV[i][j][r];
          float T = 28.f * accT[i][j][r];
          float ev4 = __expf((V - 28.f) * 0.25f);
          float et4 = __expf((T - 28.f) * 0.25f);
          float ev2 = ev4 * ev4, et2 = et4 * et4;
          s0 += ev2 * ev2;
          s1 += V;
          s2 += et2 * et2;
          s3 += T;
          s6 += ev4;
          s7 += et4;
          s8 += ev4 * (V - T);
        }
      }
#pragma unroll
      for (int o = 1; o < 16; o <<= 1) {
        s0 += __shfl_xor(s0, o, 64); s1 += __shfl_xor(s1, o, 64);
        s2 += __shfl_xor(s2, o, 64); s3 += __shfl_xor(s3, o, 64);
        s6 += __shfl_xor(s6, o, 64); s7 += __shfl_xor(s7, o, 64);
        s8 += __shfl_xor(s8, o, 64);
      }
      if (m == 0) {
        atomicAdd(&qsum[0 * 128 + rowl], s0);
        atomicAdd(&qsum[1 * 128 + rowl], s1);
        atomicAdd(&qsum[2 * 128 + rowl], s2);
        atomicAdd(&qsum[3 * 128 + rowl], s3);
        atomicAdd(&qsum[4 * 128 + rowl], s6);
        atomicAdd(&qsum[5 * 128 + rowl], s7);
        atomicAdd(&qsum[6 * 128 + rowl], s8);
      }
    }
  }
  __syncthreads();
  if (tid < 128) {
    size_t base = (size_t)ct * Bn + r0 + tid;
    const size_t qs = (size_t)NCTL * Bn;
    part[0 * qs + base] = qsum[0 * 128 + tid];
    part[1 * qs + base] = qsum[1 * 128 + tid];
    part[2 * qs + base] = qsum[2 * 128 + tid];
    part[3 * qs + base] = qsum[3 * 128 + tid];
    part[6 * qs + base] = qsum[4 * 128 + tid];
    part[7 * qs + base] = qsum[5 * 128 + tid];
    part[8 * qs + base] = qsum[6 * 128 + tid];
  }
}

// ---------- filter logits GEMM (F = tn@Wtn) + 2 row quantities ----------
__global__ __launch_bounds__(256, 2) void logits_f_k(
    const unsigned short* __restrict__ tnh, const unsigned short* __restrict__ WtnT,
    float* __restrict__ part) {
  __shared__ __align__(16) unsigned short Aa[128 * 64];
  __shared__ __align__(16) unsigned short Bs[128 * 64];
  __shared__ float qsum[2 * 128];

  const int rt = blockIdx.x, ct = blockIdx.y;
  const int r0 = rt * 128, c0 = ct * 128;
  const int tid = threadIdx.x;
  const int lane = tid & 63;
  const int wid = tid >> 6;
  const int wr = (wid >> 1) * 64, wc = (wid & 1) * 64;
  const int m = lane & 15, q = lane >> 4;

  for (int t = tid; t < 2 * 128; t += 256) qsum[t] = 0.f;

  const f32x4 zero4 = {0.f, 0.f, 0.f, 0.f};
  f32x4 acc[4][4];
#pragma unroll
  for (int i = 0; i < 4; ++i)
#pragma unroll
    for (int j = 0; j < 4; ++j) acc[i][j] = zero4;

  const int srow = tid >> 3;
  const int skc = (tid & 7) * 8;

  for (int kk = 0; kk < 16; ++kk) {
    const int k0 = kk * 64;
#pragma unroll
    for (int p = 0; p < 4; ++p) {
      stage16(tnh + (size_t)(r0 + p * 32 + srow) * Dn + k0 + skc, Aa + p * 2048 + tid * 8);
      stage16(WtnT + (size_t)(c0 + p * 32 + srow) * Dn + k0 + skc, Bs + p * 2048 + tid * 8);
    }
    __syncthreads();
#pragma unroll
    for (int ks = 0; ks < 2; ++ks) {
      bf16x8 aa[4], bb[4];
#pragma unroll
      for (int f = 0; f < 4; ++f) {
        aa[f] = *(const bf16x8*)(Aa + (wr + f * 16 + m) * 64 + ks * 32 + q * 8);
        bb[f] = *(const bf16x8*)(Bs + (wc + f * 16 + m) * 64 + ks * 32 + q * 8);
      }
#pragma unroll
      for (int i = 0; i < 4; ++i)
#pragma unroll
        for (int j = 0; j < 4; ++j)
          acc[i][j] = __builtin_amdgcn_mfma_f32_16x16x32_bf16(aa[i], bb[j], acc[i][j], 0, 0, 0);
    }
    __syncthreads();
  }

#pragma unroll
  for (int i = 0; i < 4; ++i) {
#pragma unroll
    for (int r = 0; r < 4; ++r) {
      const int rowl = wr + i * 16 + q * 4 + r;
      float s4 = 0.f, s5 = 0.f;
#pragma unroll
      for (int j = 0; j < 4; ++j) {
        int col = c0 + wc + j * 16 + m;
        if (col < Cn) {
          float F = 28.f * acc[i][j][r];
          s4 += __expf(F - 28.f);
          s5 += F;
        }
      }
#pragma unroll
      for (int o = 1; o < 16; o <<= 1) {
        s4 += __shfl_xor(s4, o, 64);
        s5 += __shfl_xor(s5, o, 64);
      }
      if (m == 0) {
        atomicAdd(&qsum[0 * 128 + rowl], s4);
        atomicAdd(&qsum[1 * 128 + rowl], s5);
      }
    }
  }
  __syncthreads();
  if (tid < 128) {
    size_t base = (size_t)ct * Bn + r0 + tid;
    const size_t qs = (size_t)NCTL * Bn;
    part[4 * qs + base] = qsum[0 * 128 + tid];
    part[5 * qs + base] = qsum[1 * 128 + tid];
  }
}

// ---------- symmetric gram (fp32 out): G = A@A^T, triangular grid + mirror ----------
__global__ __launch_bounds__(256, 2) void gramsym_f32_k(const unsigned short* __restrict__ A,
                                                        float* __restrict__ G) {
  __shared__ __align__(16) unsigned short Aa[128 * 64];
  __shared__ __align__(16) unsigned short Bs[128 * 64];
  int t = blockIdx.x, it = 0, rem = NT;
  while (t >= rem) { t -= rem; ++it; --rem; }
  const int jt = it + t;
  const int i0 = it * 128, j0 = jt * 128;
  const int tid = threadIdx.x;
  const int lane = tid & 63;
  const int wid = tid >> 6;
  const int wr = (wid >> 1) * 64, wc = (wid & 1) * 64;
  const int m = lane & 15, q = lane >> 4;

  const f32x4 zero4 = {0.f, 0.f, 0.f, 0.f};
  f32x4 acc[4][4];
#pragma unroll
  for (int i = 0; i < 4; ++i)
#pragma unroll
    for (int j = 0; j < 4; ++j) acc[i][j] = zero4;

  const int srow = tid >> 3;
  const int skc = (tid & 7) * 8;

  for (int kk = 0; kk < 16; ++kk) {
    const int k0 = kk * 64;
#pragma unroll
    for (int p = 0; p < 4; ++p) {
      stage16(A + (size_t)(i0 + p * 32 + srow) * Dn + k0 + skc, Aa + p * 2048 + tid * 8);
      stage16(A + (size_t)(j0 + p * 32 + srow) * Dn + k0 + skc, Bs + p * 2048 + tid * 8);
    }
    __syncthreads();
#pragma unroll
    for (int ks = 0; ks < 2; ++ks) {
      bf16x8 aa[4], bb[4];
#pragma unroll
      for (int f = 0; f < 4; ++f) {
        aa[f] = *(const bf16x8*)(Aa + (wr + f * 16 + m) * 64 + ks * 32 + q * 8);
        bb[f] = *(const bf16x8*)(Bs + (wc + f * 16 + m) * 64 + ks * 32 + q * 8);
      }
#pragma unroll
      for (int i = 0; i < 4; ++i)
#pragma unroll
        for (int j = 0; j < 4; ++j)
          acc[i][j] = __builtin_amdgcn_mfma_f32_16x16x32_bf16(aa[i], bb[j], acc[i][j], 0, 0, 0);
    }
    __syncthreads();
  }
#pragma unroll
  for (int i = 0; i < 4; ++i)
#pragma unroll
    for (int j = 0; j < 4; ++j)
#pragma unroll
      for (int r = 0; r < 4; ++r) {
        int row = wr + i * 16 + q * 4 + r, col = wc + j * 16 + m;
        G[(size_t)(i0 + row) * Bn + j0 + col] = acc[i][j][r];
        if (it != jt) G[(size_t)(j0 + col) * Bn + i0 + row] = acc[i][j][r];
      }
}

// ---------- symmetric gram (bf16 out): Gt = A@A^T ----------
__global__ __launch_bounds__(256, 2) void gramsym_bf16_k(const unsigned short* __restrict__ A,
                                                         unsigned short* __restrict__ G) {
  __shared__ __align__(16) unsigned short Aa[128 * 64];
  __shared__ __align__(16) unsigned short Bs[128 * 64];
  int t = blockIdx.x, it = 0, rem = NT;
  while (t >= rem) { t -= rem; ++it; --rem; }
  const int jt = it + t;
  const int i0 = it * 128, j0 = jt * 128;
  const int tid = threadIdx.x;
  const int lane = tid & 63;
  const int wid = tid >> 6;
  const int wr = (wid >> 1) * 64, wc = (wid & 1) * 64;
  const int m = lane & 15, q = lane >> 4;

  const f32x4 zero4 = {0.f, 0.f, 0.f, 0.f};
  f32x4 acc[4][4];
#pragma unroll
  for (int i = 0; i < 4; ++i)
#pragma unroll
    for (int j = 0; j < 4; ++j) acc[i][j] = zero4;

  const int srow = tid >> 3;
  const int skc = (tid & 7) * 8;

  for (int kk = 0; kk < 16; ++kk) {
    const int k0 = kk * 64;
#pragma unroll
    for (int p = 0; p < 4; ++p) {
      stage16(A + (size_t)(i0 + p * 32 + srow) * Dn + k0 + skc, Aa + p * 2048 + tid * 8);
      stage16(A + (size_t)(j0 + p * 32 + srow) * Dn + k0 + skc, Bs + p * 2048 + tid * 8);
    }
    __syncthreads();
#pragma unroll
    for (int ks = 0; ks < 2; ++ks) {
      bf16x8 aa[4], bb[4];
#pragma unroll
      for (int f = 0; f < 4; ++f) {
        aa[f] = *(const bf16x8*)(Aa + (wr + f * 16 + m) * 64 + ks * 32 + q * 8);
        bb[f] = *(const bf16x8*)(Bs + (wc + f * 16 + m) * 64 + ks * 32 + q * 8);
      }
#pragma unroll
      for (int i = 0; i < 4; ++i)
#pragma unroll
        for (int j = 0; j < 4; ++j)
          acc[i][j] = __builtin_amdgcn_mfma_f32_16x16x32_bf16(aa[i], bb[j], acc[i][j], 0, 0, 0);
    }
    __syncthreads();
  }
#pragma unroll
  for (int i = 0; i < 4; ++i)
#pragma unroll
    for (int j = 0; j < 4; ++j)
#pragma unroll
      for (int r = 0; r < 4; ++r) {
        int row = wr + i * 16 + q * 4 + r, col = wc + j * 16 + m;
        unsigned short h = f2bf(acc[i][j][r]);
        G[(size_t)(i0 + row) * Bn + j0 + col] = h;
        if (it != jt) G[(size_t)(j0 + col) * Bn + i0 + row] = h;
      }
}

// ---------- global-align GEMM: sim = vnh @ tnh^T fused loss ----------
__global__ __launch_bounds__(256, 2) void align_k(const unsigned short* __restrict__ vnh,
                                                  const unsigned short* __restrict__ tnh,
                                                  const int* __restrict__ labels,
                                                  float* __restrict__ accbuf) {
  __shared__ __align__(16) unsigned short Aa[128 * 64];
  __shared__ __align__(16) unsigned short Bs[128 * 64];
  __shared__ int li_s[128], lj_s[128];
  __shared__ float sb[4];
  const int jt = blockIdx.x, it = blockIdx.y;
  const int j0 = jt * 128, i0 = it * 128;
  const int tid = threadIdx.x;
  const int lane = tid & 63;
  const int wid = tid >> 6;
  const int wr = (wid >> 1) * 64, wc = (wid & 1) * 64;
  const int m = lane & 15, q = lane >> 4;

  if (tid < 128) li_s[tid] = labels[i0 + tid];
  else lj_s[tid - 128] = labels[j0 + tid - 128];

  const f32x4 zero4 = {0.f, 0.f, 0.f, 0.f};
  f32x4 acc[4][4];
#pragma unroll
  for (int i = 0; i < 4; ++i)
#pragma unroll
    for (int j = 0; j < 4; ++j) acc[i][j] = zero4;

  const int srow = tid >> 3;
  const int skc = (tid & 7) * 8;

  for (int kk = 0; kk < 16; ++kk) {
    const int k0 = kk * 64;
#pragma unroll
    for (int p = 0; p < 4; ++p) {
      stage16(vnh + (size_t)(i0 + p * 32 + srow) * Dn + k0 + skc, Aa + p * 2048 + tid * 8);
      stage16(tnh + (size_t)(j0 + p * 32 + srow) * Dn + k0 + skc, Bs + p * 2048 + tid * 8);
    }
    __syncthreads();
#pragma unroll
    for (int ks = 0; ks < 2; ++ks) {
      bf16x8 aa[4], bb[4];
#pragma unroll
      for (int f = 0; f < 4; ++f) {
        aa[f] = *(const bf16x8*)(Aa + (wr + f * 16 + m) * 64 + ks * 32 + q * 8);
        bb[f] = *(const bf16x8*)(Bs + (wc + f * 16 + m) * 64 + ks * 32 + q * 8);
      }
#pragma unroll
      for (int i = 0; i < 4; ++i)
#pragma unroll
        for (int j = 0; j < 4; ++j)
          acc[i][j] = __builtin_amdgcn_mfma_f32_16x16x32_bf16(aa[i], bb[j], acc[i][j], 0, 0, 0);
    }
    __syncthreads();
  }

  float ls = 0.f;
#pragma unroll
  for (int i = 0; i < 4; ++i)
#pragma unroll
    for (int r = 0; r < 4; ++r) {
      int li = li_s[wr + i * 16 + q * 4 + r];
#pragma unroll
      for (int j = 0; j < 4; ++j) {
        int lj = lj_s[wc + j * 16 + m];
        float s = acc[i][j][r];
        float x = (li == lj) ? (-10.f * (s - 0.6f)) : (40.f * (s - 0.4f));
        ls += fmaxf(x, 0.f) + __logf(1.f + __expf(-fabsf(x)));
      }
    }
  float tot = blk_sum256(ls, sb);
  if (tid == 0) atomicAdd(&accbuf[1], tot);
}

// ---------- picked-label logits + feature-distance per row (bf16 inputs) ----------
__global__ __launch_bounds__(256) void picked_k(const unsigned short* __restrict__ vnh,
                                                const unsigned short* __restrict__ tnh,
                                                const unsigned short* __restrict__ WnT,
                                                const unsigned short* __restrict__ WtnT,
                                                const int* __restrict__ labels,
                                                float* __restrict__ pv, float* __restrict__ pt,
                                                float* __restrict__ pf, float* __restrict__ df) {
  __shared__ float sb[4];
  int r = blockIdx.x;
  int lab = labels[r];
  float spv = 0.f, spt = 0.f, spf = 0.f, sdf = 0.f;
  for (int k = threadIdx.x; k < Dn; k += 256) {
    float a = bf2f(vnh[(size_t)r * Dn + k]);
    float b = bf2f(tnh[(size_t)r * Dn + k]);
    float w = bf2f(WnT[(size_t)lab * Dn + k]);
    float wt = bf2f(WtnT[(size_t)lab * Dn + k]);
    spv += a * w;
    spt += b * w;
    spf += b * wt;
    float dd = a - b;
    sdf += dd * dd;
  }
  spv = blk_sum256(spv, sb);
  spt = blk_sum256(spt, sb);
  spf = blk_sum256(spf, sb);
  sdf = blk_sum256(sdf, sb);
  if (threadIdx.x == 0) {
    pv[r] = 28.f * spv;
    pt[r] = 28.f * spt;
    pf[r] = 28.f * spf;
    df[r] = sdf;
  }
}

// ---------- reduce partials + per-row CE/KL/dist ----------
__global__ __launch_bounds__(256) void finalize_k(const float* __restrict__ part,
                                                  const float* __restrict__ pv,
                                                  const float* __restrict__ pt,
                                                  const float* __restrict__ pf,
                                                  const float* __restrict__ df,
                                                  float* __restrict__ accbuf) {
  __shared__ float sb[4];
  int r = blockIdx.x * 256 + threadIdx.x;
  float s[NQ];
#pragma unroll
  for (int q = 0; q < NQ; ++q) s[q] = 0.f;
  const size_t qs = (size_t)NCTL * Bn;
  for (int ct = 0; ct < NCTL; ++ct) {
#pragma unroll
    for (int q = 0; q < NQ; ++q) s[q] += part[(size_t)q * qs + (size_t)ct * Bn + r];
  }
  float lseV = logf(s[0]) + 28.f;
  float lseT = logf(s[2]) + 28.f;
  float lseF = logf(s[4]) + 28.f;
  const float invC = 1.f / (float)Cn;
  float ceV = -(0.9f * (pv[r] - lseV) + 0.1f * invC * (s[1] - (float)Cn * lseV));
  float ceT = -(0.9f * (pt[r] - lseT) + 0.1f * invC * (s[3] - (float)Cn * lseT));
  float ceF = -(0.9f * (pf[r] - lseF) + 0.1f * invC * (s[5] - (float)Cn * lseF));
  float kl = s[8] / (4.f * s[6]) + logf(s[7]) - logf(s[6]);
  float row = ceV + ceT + ceF + kl + df[r];
  float tot = blk_sum256(row, sb);
  if (threadIdx.x == 0) atomicAdd(&accbuf[0], tot / (float)Bn);
}

// ---------- HardDarkRank: swizzled-LDS selection + Gt lookup ----------
__device__ __forceinline__ int kswz(int j) {
  return (j & ~63) | ((j ^ (j >> 6)) & 63);
}
__device__ __forceinline__ unsigned long long shflx_u64(unsigned long long v, int o) {
  int lo = __shfl_xor((int)(unsigned)v, o, 64);
  int hi = __shfl_xor((int)(unsigned)(v >> 32), o, 64);
  return ((unsigned long long)(unsigned)hi << 32) | (unsigned)lo;
}

__global__ __launch_bounds__(256) void hdr_k(const float* __restrict__ Gv,
                                             const unsigned short* __restrict__ Gtb,
                                             const float* __restrict__ sqv,
                                             const float* __restrict__ sqt,
                                             float* __restrict__ accbuf) {
  __shared__ float key[Bn];
  __shared__ int selIdx[64];
  __shared__ float selS[64];
  const int i = blockIdx.x, tid = threadIdx.x;
  const int lane = tid & 63, wid = tid >> 6;
  const float INF = __builtin_inff();
  float sqi = sqv[i];
  const float4* gv4 = (const float4*)(Gv + (size_t)i * Bn);
  const float4* sq4 = (const float4*)sqv;
  for (int j4 = tid; j4 < Bn / 4; j4 += 256) {
    float4 g = gv4[j4];
    float4 s = sq4[j4];
    int j = j4 * 4;
    key[kswz(j + 0)] = (j + 0 == i) ? INF : fmaxf(sqi + s.x - 2.f * g.x, 1e-12f);
    key[kswz(j + 1)] = (j + 1 == i) ? INF : fmaxf(sqi + s.y - 2.f * g.y, 1e-12f);
    key[kswz(j + 2)] = (j + 2 == i) ? INF : fmaxf(sqi + s.z - 2.f * g.z, 1e-12f);
    key[kswz(j + 3)] = (j + 3 == i) ? INF : fmaxf(sqi + s.w - 2.f * g.w, 1e-12f);
  }
  __syncthreads();

  if (wid == 0) {
    // lane owns segment {j : j % 64 == lane}; swizzled reads are conflict-free
    unsigned long long best = ~0ull;
    for (int k = 0; k < 64; ++k) {
      int j = k * 64 + lane;
      float v = key[kswz(j)];
      unsigned long long p = ((unsigned long long)__float_as_uint(v) << 32) | (unsigned)j;
      if (p < best) best = p;
    }
    for (int it = 0; it < 63; ++it) {
      unsigned long long w = best;
#pragma unroll
      for (int o = 32; o > 0; o >>= 1) {
        unsigned long long ow = shflx_u64(w, o);
        if (ow < w) w = ow;
      }
      int bj = (int)(unsigned)w;
      if (lane == 0) selIdx[it] = bj;
      int s = bj & 63;
      int kj = (lane << 6) | s;
      int sidx = kswz(kj);
      float kv = key[sidx];
      if (kj == bj) { kv = INF; key[sidx] = INF; }
      unsigned long long p = ((unsigned long long)__float_as_uint(kv) << 32) | (unsigned)kj;
#pragma unroll
      for (int o = 32; o > 0; o >>= 1) {
        unsigned long long op = shflx_u64(p, o);
        if (op < p) p = op;
      }
      if (lane == s) best = p;
    }
  }
  __syncthreads();

  if (tid < 63) {
    int j = selIdx[tid];
    float g = bf2f(Gtb[(size_t)i * Bn + j]);
    float d2 = fmaxf(sqt[i] + sqt[j] - 2.f * g, 1e-12f);
    selS[tid] = -3.f * sqrtf(d2) * d2;
  }
  __syncthreads();

  if (tid == 0) {
    float lse = selS[62];
    float loss = 0.f;
    for (int k = 61; k >= 0; --k) {
      float a = fmaxf(lse, selS[k]);
      lse = a + logf(__expf(lse - a) + __expf(selS[k] - a));
      loss += lse - selS[k];
    }
    atomicAdd(&accbuf[2], loss);
  }
}

__global__ void combine_k(const float* __restrict__ accbuf, float* __restrict__ out) {
  out[0] = accbuf[0] + (2.f / (float)Bn) * accbuf[1] + (0.1f / (float)Bn) * accbuf[2];
}

// ---------- launch ----------
extern "C" void kernel_launch(void* const* d_in, const int* in_sizes, int n_in,
                              void* d_out, int out_size, void* d_ws, size_t ws_size,
                              hipStream_t stream) {
  const float* ve = (const float*)d_in[0];
  const float* te = (const float*)d_in[1];
  const int* labels = (const int*)d_in[2];
  const float* W = (const float*)d_in[3];
  const float* Wt = (const float*)d_in[4];
  float* out = (float*)d_out;

  char* base = (char*)d_ws;
  size_t off = 0;
  unsigned short* vnh = (unsigned short*)(base + off);  off += (size_t)Bn * Dn * 2;
  unsigned short* tnh = (unsigned short*)(base + off);  off += (size_t)Bn * Dn * 2;
  unsigned short* WnT = (unsigned short*)(base + off);  off += (size_t)Cpad * Dn * 2;
  unsigned short* WtnT = (unsigned short*)(base + off); off += (size_t)Cpad * Dn * 2;
  float* Gv = (float*)(base + off);          off += (size_t)Bn * Bn * 4;
  unsigned short* Gtb = (unsigned short*)(base + off); off += (size_t)Bn * Bn * 2;
  float* part = (float*)(base + off);        off += (size_t)NQ * NCTL * Bn * 4;
  float* rnW = (float*)(base + off);         off += (size_t)Cpad * 4;
  float* rnWt = (float*)(base + off);        off += (size_t)Cpad * 4;
  float* sqv = (float*)(base + off);         off += (size_t)Bn * 4;
  float* sqt = (float*)(base + off);         off += (size_t)Bn * 4;
  float* pv = (float*)(base + off);          off += (size_t)Bn * 4;
  float* pt = (float*)(base + off);          off += (size_t)Bn * 4;
  float* pf = (float*)(base + off);          off += (size_t)Bn * 4;
  float* df = (float*)(base + off);          off += (size_t)Bn * 4;
  float* acc = (float*)(base + off);         off += 64;

  zero_acc_k<<<1, 64, 0, stream>>>(acc);
  rownorm_k<<<Bn, 256, 0, stream>>>(ve, vnh, sqv);
  rownorm_k<<<Bn, 256, 0, stream>>>(te, tnh, sqt);
  colnorm_k<<<(Cn + 255) / 256, 256, 0, stream>>>(W, rnW);
  colnorm_k<<<(Cn + 255) / 256, 256, 0, stream>>>(Wt, rnWt);
  transpose_k<<<dim3(Cpad / 64, Dn / 64), 256, 0, stream>>>(W, rnW, WnT);
  transpose_k<<<dim3(Cpad / 64, Dn / 64), 256, 0, stream>>>(Wt, rnWt, WtnT);
  logits_vt_k<<<dim3(Bn / 128, NCTL), 256, 0, stream>>>(vnh, tnh, WnT, part);
  logits_f_k<<<dim3(Bn / 128, NCTL), 256, 0, stream>>>(tnh, WtnT, part);
  gramsym_f32_k<<<NTRI, 256, 0, stream>>>(vnh, Gv);
  gramsym_bf16_k<<<NTRI, 256, 0, stream>>>(tnh, Gtb);
  align_k<<<dim3(Bn / 128, Bn / 128), 256, 0, stream>>>(vnh, tnh, labels, acc);
  picked_k<<<Bn, 256, 0, stream>>>(vnh, tnh, WnT, WtnT, labels, pv, pt, pf, df);
  finalize_k<<<Bn / 256, 256, 0, stream>>>(part, pv, pt, pf, df, acc);
  hdr_k<<<Bn, 256, 0, stream>>>(Gv, Gtb, sqv, sqt, acc);
  combine_k<<<1, 1, 0, stream>>>(acc, out);
}